// Round 11
// baseline (63.797 us; speedup 1.0000x reference)
//
#include <hip/hip_runtime.h>
#include <math.h>

#define NC    64
#define NT    128
#define NS    8
#define NFEAT 16
#define NE1   4032
#define NB    1024

typedef __attribute__((ext_vector_type(8))) short short8v;   // 8 bf16 carrier
typedef __attribute__((ext_vector_type(4))) float float4v;

__device__ __forceinline__ float sigmoidf_(float x) { return 1.f / (1.f + expf(-x)); }

__device__ __forceinline__ unsigned short bf16hi(float v) {
  return (unsigned short)(__float_as_uint(v) >> 16);
}
__device__ __forceinline__ float bf16hi_f(float v) {
  return __uint_as_float(__float_as_uint(v) & 0xffff0000u);
}

// ---------------------------------------------------------------------------
// Kernel A (unchanged from round 10, verified): block = (s, nt): build M_s,
// compute rows [nt*16, nt*16+16) of P2, P3, pack A-operand MFMA fragments
// (hi/lo bf16 split) in mfma_f32_16x16x32_bf16 A-layout: lane l holds
// A[row = nt*16 + (l&15)][k = 32*t6 + 8*(l>>4) + e], k-concat = [M|P2|P3].
// Afrag uint layout: [s][t6(6)][nt(4)][half(2)][lane(64)][4] (12288/step).
// ---------------------------------------------------------------------------
__global__ __launch_bounds__(256) void build_frags_kernel(
    const int* __restrict__ ei, long long E_total,
    const float* __restrict__ ew, unsigned int* __restrict__ Afrag) {
  const int s  = blockIdx.x & 7;
  const int nt = blockIdx.x >> 3;
  const int t  = threadIdx.x;
  const int lane = t & 63;

  __shared__ float M[64][64];       // M[c][r]
  __shared__ float P23[2][16][64];  // local rows of P2, P3
  __shared__ float deg[64];

  for (int i = t; i < 4096; i += 256) (&M[0][0])[i] = 0.f;
  if (t < 64) deg[t] = 0.f;
  __syncthreads();

  const int* row = ei;
  const int* col = ei + E_total;
  const float* w = ew + s * NE1;
  for (int e = t; e < NE1; e += 256) atomicAdd(&deg[col[e]], w[e]);
  __syncthreads();
  if (t < 64) { float d = deg[t]; deg[t] = (d > 0.f) ? rsqrtf(d) : 0.f; }
  __syncthreads();
  for (int e = t; e < NE1; e += 256) {
    int r = row[e], c = col[e];
    atomicAdd(&M[c][r], deg[r] * w[e] * deg[c]);
  }
  __syncthreads();

  {
    const int rowl = ((t >> 6) << 2) | (lane >> 4);   // 0..15
    const int i    = (nt << 4) | rowl;
    const int jg4  = (lane & 15) << 2;
    float4v a2 = {0.f, 0.f, 0.f, 0.f};
#pragma unroll 8
    for (int m = 0; m < 64; ++m) {
      const float pim = M[i][m];
      const float4v mj = *(const float4v*)(&M[m][jg4]);
      a2 += pim * mj;
    }
    *(float4v*)(&P23[0][rowl][jg4]) = a2;
    float4v a3 = {0.f, 0.f, 0.f, 0.f};
#pragma unroll 8
    for (int m = 0; m < 64; ++m) {
      const float v2m = P23[0][rowl][m];              // same-wave DS ordering
      const float4v mj = *(const float4v*)(&M[m][jg4]);
      a3 += v2m * mj;
    }
    *(float4v*)(&P23[1][rowl][jg4]) = a3;
  }
  __syncthreads();

  for (int slot = t; slot < 768; slot += 256) {
    const int t6 = slot >> 7;
    const int h  = (slot >> 6) & 1;
    const int lf = slot & 63;
    const int rl = lf & 15;
    const int kb = (t6 << 5) | ((lf >> 4) << 3);
    uint4 u;
    unsigned int uu[4];
#pragma unroll
    for (int j = 0; j < 4; ++j) {
      unsigned short us[2];
#pragma unroll
      for (int e2 = 0; e2 < 2; ++e2) {
        const int k  = kb + (j << 1) + e2;
        const int kk = k >> 6;
        const int m  = k & 63;
        const float v = (kk == 0) ? M[(nt << 4) | rl][m] : P23[kk - 1][rl][m];
        us[e2] = h ? bf16hi(v - bf16hi_f(v)) : bf16hi(v);
      }
      uu[j] = (unsigned int)us[0] | ((unsigned int)us[1] << 16);
    }
    u.x = uu[0]; u.y = uu[1]; u.z = uu[2]; u.w = uu[3];
    unsigned int* dst = Afrag + ((((size_t)(s * 6 + t6) * 4 + nt) * 2 + h) << 8) + (lf << 2);
    *(uint4*)dst = u;
  }
}

// ---------------------------------------------------------------------------
// Kernel B: FULLY FUSED TAGConv (MFMA, 4-graph column packing) + ReLU +
// max-pool + LSTM + FC. Block = 4 waves = 4 graphs; wave w handles steps
// w and w+4 (zT/V0T reused wave-locally between iterations, in-order DS).
// B-columns pack 4 graphs: col = 4*g + o, so ONE mfma serves 4 graphs
// (no wasted tile columns). A-frags stream from global/L2 (shared by all
// 4 graphs). acc += Ahi*Bhi + Alo*Bhi + Ahi*Blo (Alo*Blo ~2^-16, dropped).
// After both step-iterations: __syncthreads, threads 0..3 run the 8-step
// LSTM + FC for one graph each from pooled LDS. out = [1024][2] f32.
// ---------------------------------------------------------------------------
__global__ __launch_bounds__(256) void tag_lstm_kernel(
    const float* __restrict__ x, const unsigned int* __restrict__ Afrag,
    const float* __restrict__ lin_w, const float* __restrict__ lin_b,
    const float* __restrict__ w_ih, const float* __restrict__ b_ih,
    const float* __restrict__ w_hh, const float* __restrict__ b_hh,
    const float* __restrict__ fc_w, const float* __restrict__ fc_b,
    float* __restrict__ out) {
  const int t    = threadIdx.x;
  const int lane = t & 63;
  const int w    = t >> 6;
  const int g0   = blockIdx.x << 2;            // 4 graphs per block
  const int col  = lane & 15;                  // B/C column = 4*g + o

  __shared__ __align__(16) unsigned short zT[4][2][3][16][80]; // [w][h][kk][col][m pad80]
  __shared__ __align__(16) float V0T[4][16][72];               // [w][col][n pad72]
  __shared__ float pooled_lds[4][NS][4];                       // [g][s][o]

  // bias column sum (uniform scalar loads)
  const float bsA = lin_b[0] + lin_b[4] + lin_b[8]  + lin_b[12];
  const float bsB = lin_b[1] + lin_b[5] + lin_b[9]  + lin_b[13];
  const float bsC = lin_b[2] + lin_b[6] + lin_b[10] + lin_b[14];
  const float bsD = lin_b[3] + lin_b[7] + lin_b[11] + lin_b[15];
  const int oq = col & 3;
  const float bs = (oq == 0) ? bsA : (oq == 1) ? bsB : (oq == 2) ? bsC : bsD;

#pragma unroll 1
  for (int it = 0; it < 2; ++it) {
    const int s = w + (it << 2);               // wave w -> steps w, w+4

    // x loads: 4 graphs x 16 floats per lane (row = node = lane)
    float xf[4][16];
#pragma unroll
    for (int g = 0; g < 4; ++g) {
      const float* xr = x + (((size_t)(g0 + g) << 6) + lane) * NT + s * NFEAT;
#pragma unroll
      for (int i = 0; i < 4; ++i)
        *(float4*)(&xf[g][i << 2]) = *(const float4*)(xr + (i << 2));
    }

    // stage 1: V[g][k][o] = sum_f x[g][f]*W[k*4+o][f]; W uniform scalar loads
#pragma unroll
    for (int ko = 0; ko < 16; ++ko) {
      const float* wr = lin_w + ko * 16;
      float a[4] = {0.f, 0.f, 0.f, 0.f};
#pragma unroll
      for (int f = 0; f < 16; ++f) {
        const float wv = wr[f];
#pragma unroll
        for (int g = 0; g < 4; ++g) a[g] = fmaf(xf[g][f], wv, a[g]);
      }
      const int k = ko >> 2, o = ko & 3;
#pragma unroll
      for (int g = 0; g < 4; ++g) {
        const int cl = (g << 2) | o;
        if (k == 0) {
          V0T[w][cl][lane] = a[g];
        } else {
          zT[w][0][k - 1][cl][lane] = bf16hi(a[g]);
          zT[w][1][k - 1][cl][lane] = bf16hi(a[g] - bf16hi_f(a[g]));
        }
      }
    }
    // wave-local LDS write->read: no barrier needed

    // main loop: 6 k-steps of 32; A from global/L2, B from per-wave LDS
    float4v acc[4];
#pragma unroll
    for (int nt = 0; nt < 4; ++nt) acc[nt] = (float4v){0.f, 0.f, 0.f, 0.f};

    const unsigned int* Ab = Afrag + (size_t)s * 12288 + (lane << 2);
#pragma unroll 2
    for (int t6 = 0; t6 < 6; ++t6) {
      short8v Ah[4], Al[4];
#pragma unroll
      for (int nt = 0; nt < 4; ++nt) {
        Ah[nt] = *(const short8v*)(Ab + ((((t6 << 2) | nt) << 1) << 8));
        Al[nt] = *(const short8v*)(Ab + (((((t6 << 2) | nt) << 1) | 1) << 8));
      }
      const int kk   = t6 >> 1;
      const int mloc = ((t6 & 1) << 5) | ((lane >> 4) << 3);
      const short8v Bh = *(const short8v*)(&zT[w][0][kk][col][mloc]);
      const short8v Bl = *(const short8v*)(&zT[w][1][kk][col][mloc]);
#pragma unroll
      for (int nt = 0; nt < 4; ++nt) {
        acc[nt] = __builtin_amdgcn_mfma_f32_16x16x32_bf16(Ah[nt], Bh, acc[nt], 0, 0, 0);
        acc[nt] = __builtin_amdgcn_mfma_f32_16x16x32_bf16(Al[nt], Bh, acc[nt], 0, 0, 0);
        acc[nt] = __builtin_amdgcn_mfma_f32_16x16x32_bf16(Ah[nt], Bl, acc[nt], 0, 0, 0);
      }
    }

    // epilogue: + V0 + bias, relu, max over 64 rows; lanes 0..15 store
    float mx = 0.f;   // relu floor
#pragma unroll
    for (int nt = 0; nt < 4; ++nt) {
      const float4v v0 = *(const float4v*)(&V0T[w][col][(nt << 4) | ((lane >> 4) << 2)]);
#pragma unroll
      for (int r = 0; r < 4; ++r) {
        float ov = acc[nt][r] + v0[r] + bs;
        ov = fmaxf(ov, 0.f);
        mx = fmaxf(mx, ov);
      }
    }
    mx = fmaxf(mx, __shfl_xor(mx, 16));
    mx = fmaxf(mx, __shfl_xor(mx, 32));
    if (lane < 16) pooled_lds[col >> 2][s][col & 3] = mx;
  }

  __syncthreads();

  // LSTM + FC: threads 0..3, one graph each, from pooled LDS
  if (t < 4) {
    float h[4] = {0.f, 0.f, 0.f, 0.f};
    float c[4] = {0.f, 0.f, 0.f, 0.f};
    for (int s = 0; s < NS; ++s) {
      const float xv[4] = {pooled_lds[t][s][0], pooled_lds[t][s][1],
                           pooled_lds[t][s][2], pooled_lds[t][s][3]};
      float gates[16];
#pragma unroll
      for (int j = 0; j < 16; ++j) {
        float acc = b_ih[j] + b_hh[j];
#pragma unroll
        for (int q = 0; q < 4; ++q) {
          acc = fmaf(xv[q], w_ih[j * 4 + q], acc);
          acc = fmaf(h[q], w_hh[j * 4 + q], acc);
        }
        gates[j] = acc;
      }
#pragma unroll
      for (int q = 0; q < 4; ++q) {
        float ig = sigmoidf_(gates[q]);
        float fg = sigmoidf_(gates[4 + q]);
        float gg = tanhf(gates[8 + q]);
        float og = sigmoidf_(gates[12 + q]);
        float cc = fmaf(fg, c[q], ig * gg);
        c[q] = cc;
        h[q] = og * tanhf(cc);
      }
    }
    float o0 = fc_b[0], o1 = fc_b[1];
#pragma unroll
    for (int q = 0; q < 4; ++q) {
      o0 = fmaf(h[q], fc_w[q], o0);
      o1 = fmaf(h[q], fc_w[4 + q], o1);
    }
    out[(size_t)(g0 + t) * 2]     = o0;
    out[(size_t)(g0 + t) * 2 + 1] = o1;
  }
}

// ---------------------------------------------------------------------------
extern "C" void kernel_launch(void* const* d_in, const int* in_sizes, int n_in,
                              void* d_out, int out_size, void* d_ws, size_t ws_size,
                              hipStream_t stream) {
  const float* x     = (const float*)d_in[0];
  const int*   ei    = (const int*)d_in[1];
  const float* ew    = (const float*)d_in[3];
  const float* lin_w = (const float*)d_in[4];
  const float* lin_b = (const float*)d_in[5];
  const float* w_ih  = (const float*)d_in[6];
  const float* b_ih  = (const float*)d_in[7];
  const float* w_hh  = (const float*)d_in[8];
  const float* b_hh  = (const float*)d_in[9];
  const float* fc_w  = (const float*)d_in[10];
  const float* fc_b  = (const float*)d_in[11];
  float* out = (float*)d_out;

  const long long E_total = (long long)in_sizes[1] / 2;

  // ws: Afrag [8][6][4][2][64][4] uint (384 KB)
  unsigned int* Afrag = (unsigned int*)d_ws;

  hipLaunchKernelGGL(build_frags_kernel, dim3(32), dim3(256), 0, stream,
                     ei, E_total, ew, Afrag);
  hipLaunchKernelGGL(tag_lstm_kernel, dim3(NB / 4), dim3(256), 0, stream,
                     x, Afrag, lin_w, lin_b,
                     w_ih, b_ih, w_hh, b_hh, fc_w, fc_b, out);
}

// Round 12
// 58.537 us; speedup vs baseline: 1.0898x; 1.0898x over previous
//
#include <hip/hip_runtime.h>
#include <math.h>

#define NC    64
#define NT    128
#define NS    8
#define NFEAT 16
#define NE1   4032
#define NB    1024

typedef __attribute__((ext_vector_type(8))) short short8v;   // 8 bf16 carrier
typedef __attribute__((ext_vector_type(4))) float float4v;

__device__ __forceinline__ float sigmoidf_(float x) { return 1.f / (1.f + expf(-x)); }

__device__ __forceinline__ unsigned short bf16hi(float v) {
  return (unsigned short)(__float_as_uint(v) >> 16);
}
__device__ __forceinline__ float bf16hi_f(float v) {
  return __uint_as_float(__float_as_uint(v) & 0xffff0000u);
}

// ---------------------------------------------------------------------------
// Kernel A: block = (s, nt): build M_s, compute rows [nt*16, nt*16+16) of
// P2, P3, pack A-operand MFMA fragments (hi/lo bf16 split) for the K=256
// concat [I | M | P2 | P3] in mfma_f32_16x16x32_bf16 A-layout: lane l holds
// A[row = nt*16 + (l&15)][k = 32*t6 + 8*(l>>4) + e], e=0..7, t6 = 0..7.
// Afrag uint layout: [s][t6(8)][nt(4)][half(2)][lane(64)][4]
//   => per-s stride = 8*4*2*256 = 16384 uints (512 KB total).
// ---------------------------------------------------------------------------
__global__ __launch_bounds__(256) void build_frags_kernel(
    const int* __restrict__ ei, long long E_total,
    const float* __restrict__ ew, unsigned int* __restrict__ Afrag) {
  const int s  = blockIdx.x & 7;
  const int nt = blockIdx.x >> 3;
  const int t  = threadIdx.x;
  const int lane = t & 63;

  __shared__ float M[64][64];       // M[c][r]
  __shared__ float P23[2][16][64];  // local rows of P2, P3
  __shared__ float deg[64];

  for (int i = t; i < 4096; i += 256) (&M[0][0])[i] = 0.f;
  if (t < 64) deg[t] = 0.f;
  __syncthreads();

  const int* row = ei;
  const int* col = ei + E_total;
  const float* w = ew + s * NE1;
  for (int e = t; e < NE1; e += 256) atomicAdd(&deg[col[e]], w[e]);
  __syncthreads();
  if (t < 64) { float d = deg[t]; deg[t] = (d > 0.f) ? rsqrtf(d) : 0.f; }
  __syncthreads();
  for (int e = t; e < NE1; e += 256) {
    int r = row[e], c = col[e];
    atomicAdd(&M[c][r], deg[r] * w[e] * deg[c]);
  }
  __syncthreads();

  {
    const int rowl = ((t >> 6) << 2) | (lane >> 4);   // 0..15
    const int i    = (nt << 4) | rowl;
    const int jg4  = (lane & 15) << 2;
    float4v a2 = {0.f, 0.f, 0.f, 0.f};
#pragma unroll 8
    for (int m = 0; m < 64; ++m) {
      const float pim = M[i][m];
      const float4v mj = *(const float4v*)(&M[m][jg4]);
      a2 += pim * mj;
    }
    *(float4v*)(&P23[0][rowl][jg4]) = a2;
    float4v a3 = {0.f, 0.f, 0.f, 0.f};
#pragma unroll 8
    for (int m = 0; m < 64; ++m) {
      const float v2m = P23[0][rowl][m];              // same-wave DS ordering
      const float4v mj = *(const float4v*)(&M[m][jg4]);
      a3 += v2m * mj;
    }
    *(float4v*)(&P23[1][rowl][jg4]) = a3;
  }
  __syncthreads();

  // pack 1024 slots (t6 x half x lane-frag), 4 per thread
  for (int slot = t; slot < 1024; slot += 256) {
    const int t6 = slot >> 7;              // 0..7
    const int h  = (slot >> 6) & 1;
    const int lf = slot & 63;
    const int rl = lf & 15;                // local row
    const int rg = (nt << 4) | rl;         // global row
    const int kb = (t6 << 5) | ((lf >> 4) << 3);
    uint4 u;
    unsigned int uu[4];
#pragma unroll
    for (int j = 0; j < 4; ++j) {
      unsigned short us[2];
#pragma unroll
      for (int e2 = 0; e2 < 2; ++e2) {
        const int k  = kb + (j << 1) + e2;
        const int kk = k >> 6;             // 0:I, 1:M, 2:P2, 3:P3
        const int m  = k & 63;
        const float v = (kk == 0) ? ((m == rg) ? 1.0f : 0.0f)
                      : (kk == 1) ? M[rg][m]
                                  : P23[kk - 2][rl][m];
        us[e2] = h ? bf16hi(v - bf16hi_f(v)) : bf16hi(v);
      }
      uu[j] = (unsigned int)us[0] | ((unsigned int)us[1] << 16);
    }
    u.x = uu[0]; u.y = uu[1]; u.z = uu[2]; u.w = uu[3];
    unsigned int* dst = Afrag + ((((size_t)(s * 8 + t6) * 4 + nt) * 2 + h) << 8) + (lf << 2);
    *(uint4*)dst = u;
  }
}

// ---------------------------------------------------------------------------
// Kernel B: TAGConv via MFMA (K=256 concat incl. identity) + ReLU + max-pool.
// Block = (graph-quad, step): 2048 blocks x 4 waves. Wave w computes stage-1
// V (all 4 k's incl V0) for graph g0+w into BLOCK-SHARED zT (disjoint cols
// 4w+o), one barrier, then wave w computes A-row-tile nt=w: 16 A-frag b128
// global loads (L2-shared across the 256 same-s blocks) + 24 mfma.
// B-columns pack 4 graphs (col = 4g+o) -> no wasted tile columns.
// acc += Ahi*Bhi + Alo*Bhi + Ahi*Blo (Alo*Blo ~2^-16, dropped).
// LDS ~19KB -> high occupancy (VGPR-limited).
// ---------------------------------------------------------------------------
__global__ __launch_bounds__(256) void tag_pool_mfma_kernel(
    const float* __restrict__ x, const unsigned int* __restrict__ Afrag,
    const float* __restrict__ lin_w, const float* __restrict__ lin_b,
    float* __restrict__ pooled) {
  const int t    = threadIdx.x;
  const int lane = t & 63;
  const int w    = t >> 6;
  const int s    = blockIdx.x & 7;                 // step (XCD-aligned)
  const int g0   = (blockIdx.x >> 3) << 2;         // graph quad
  const int col  = lane & 15;                      // B/C column = 4*g + o

  __shared__ __align__(16) unsigned short zT[2][4][16][72]; // [h][kk][col][m pad72]
  __shared__ float pmax[4][16];

  // stage 1: wave w handles graph g0+w; lane = node.
  {
    const int g = g0 + w;
    const float* xr = x + (((size_t)g << 6) + lane) * NT + s * NFEAT;
    float xf[16];
#pragma unroll
    for (int i = 0; i < 4; ++i)
      *(float4*)(&xf[i << 2]) = *(const float4*)(xr + (i << 2));

#pragma unroll
    for (int ko = 0; ko < 16; ++ko) {
      const float* wr = lin_w + ko * 16;           // uniform scalar loads
      float a = 0.f;
#pragma unroll
      for (int f = 0; f < 16; ++f) a = fmaf(xf[f], wr[f], a);
      const int kk = ko >> 2;
      const int cl = (w << 2) | (ko & 3);
      zT[0][kk][cl][lane] = bf16hi(a);
      zT[1][kk][cl][lane] = bf16hi(a - bf16hi_f(a));
    }
  }
  __syncthreads();

  // main loop: 8 k-steps of 32; wave w owns A-row-tile nt=w.
  float4v acc = {0.f, 0.f, 0.f, 0.f};
  const unsigned int* Ab = Afrag + (size_t)s * 16384 + (lane << 2);
#pragma unroll
  for (int t6 = 0; t6 < 8; ++t6) {
    const short8v Ah = *(const short8v*)(Ab + ((((t6 << 2) | w) << 1) << 8));
    const short8v Al = *(const short8v*)(Ab + (((((t6 << 2) | w) << 1) | 1) << 8));
    const int kk   = t6 >> 1;
    const int mloc = ((t6 & 1) << 5) | ((lane >> 4) << 3);
    const short8v Bh = *(const short8v*)(&zT[0][kk][col][mloc]);
    const short8v Bl = *(const short8v*)(&zT[1][kk][col][mloc]);
    acc = __builtin_amdgcn_mfma_f32_16x16x32_bf16(Ah, Bh, acc, 0, 0, 0);
    acc = __builtin_amdgcn_mfma_f32_16x16x32_bf16(Al, Bh, acc, 0, 0, 0);
    acc = __builtin_amdgcn_mfma_f32_16x16x32_bf16(Ah, Bl, acc, 0, 0, 0);
  }

  // epilogue: + bias, relu, max over this tile's 16 rows, then block max
  const float bsA = lin_b[0] + lin_b[4] + lin_b[8]  + lin_b[12];
  const float bsB = lin_b[1] + lin_b[5] + lin_b[9]  + lin_b[13];
  const float bsC = lin_b[2] + lin_b[6] + lin_b[10] + lin_b[14];
  const float bsD = lin_b[3] + lin_b[7] + lin_b[11] + lin_b[15];
  const int oq = col & 3;
  const float bs = (oq == 0) ? bsA : (oq == 1) ? bsB : (oq == 2) ? bsC : bsD;

  float mx = 0.f;   // relu floor: outputs >= 0
#pragma unroll
  for (int r = 0; r < 4; ++r) mx = fmaxf(mx, fmaxf(acc[r] + bs, 0.f));
  mx = fmaxf(mx, __shfl_xor(mx, 16));
  mx = fmaxf(mx, __shfl_xor(mx, 32));
  if (lane < 16) pmax[w][lane] = mx;
  __syncthreads();

  if (t < 16) {
    const float m01 = fmaxf(pmax[0][t], pmax[1][t]);
    const float m23 = fmaxf(pmax[2][t], pmax[3][t]);
    pooled[((size_t)(g0 + (t >> 2)) * NS + s) * 4 + (t & 3)] = fmaxf(m01, m23);
  }
}

// ---------------------------------------------------------------------------
// Kernel C: LSTM (hidden 4, 8 steps) + FC. One thread per graph.
// ---------------------------------------------------------------------------
__global__ __launch_bounds__(64) void lstm_fc_kernel(
    const float* __restrict__ pooled,
    const float* __restrict__ w_ih, const float* __restrict__ b_ih,
    const float* __restrict__ w_hh, const float* __restrict__ b_hh,
    const float* __restrict__ fc_w, const float* __restrict__ fc_b,
    float* __restrict__ out) {
  const int g = blockIdx.x * blockDim.x + threadIdx.x;
  if (g >= NB) return;
  float h[4] = {0.f, 0.f, 0.f, 0.f};
  float c[4] = {0.f, 0.f, 0.f, 0.f};
  for (int s = 0; s < NS; ++s) {
    float4 xt4 = *(const float4*)(pooled + (((size_t)g << 3) + s) * 4);
    const float xv[4] = {xt4.x, xt4.y, xt4.z, xt4.w};
    float gates[16];
#pragma unroll
    for (int j = 0; j < 16; ++j) {
      float acc = b_ih[j] + b_hh[j];
#pragma unroll
      for (int q = 0; q < 4; ++q) {
        acc = fmaf(xv[q], w_ih[j * 4 + q], acc);
        acc = fmaf(h[q], w_hh[j * 4 + q], acc);
      }
      gates[j] = acc;
    }
#pragma unroll
    for (int q = 0; q < 4; ++q) {
      float ig = sigmoidf_(gates[q]);
      float fg = sigmoidf_(gates[4 + q]);
      float gg = tanhf(gates[8 + q]);
      float og = sigmoidf_(gates[12 + q]);
      float cc = fmaf(fg, c[q], ig * gg);
      c[q] = cc;
      h[q] = og * tanhf(cc);
    }
  }
  float o0 = fc_b[0], o1 = fc_b[1];
#pragma unroll
  for (int q = 0; q < 4; ++q) {
    o0 = fmaf(h[q], fc_w[q], o0);
    o1 = fmaf(h[q], fc_w[4 + q], o1);
  }
  out[(size_t)g * 2]     = o0;
  out[(size_t)g * 2 + 1] = o1;
}

// ---------------------------------------------------------------------------
extern "C" void kernel_launch(void* const* d_in, const int* in_sizes, int n_in,
                              void* d_out, int out_size, void* d_ws, size_t ws_size,
                              hipStream_t stream) {
  const float* x     = (const float*)d_in[0];
  const int*   ei    = (const int*)d_in[1];
  const float* ew    = (const float*)d_in[3];
  const float* lin_w = (const float*)d_in[4];
  const float* lin_b = (const float*)d_in[5];
  const float* w_ih  = (const float*)d_in[6];
  const float* b_ih  = (const float*)d_in[7];
  const float* w_hh  = (const float*)d_in[8];
  const float* b_hh  = (const float*)d_in[9];
  const float* fc_w  = (const float*)d_in[10];
  const float* fc_b  = (const float*)d_in[11];
  float* out = (float*)d_out;

  const long long E_total = (long long)in_sizes[1] / 2;

  // ws: Afrag [8][8][4][2][64][4] uint (512 KB), then pooled [1024][8][4] f32
  unsigned int* Afrag = (unsigned int*)d_ws;
  float* pooled = (float*)(Afrag + (size_t)NS * 16384);

  hipLaunchKernelGGL(build_frags_kernel, dim3(32), dim3(256), 0, stream,
                     ei, E_total, ew, Afrag);
  hipLaunchKernelGGL(tag_pool_mfma_kernel, dim3(2048), dim3(256), 0, stream,
                     x, Afrag, lin_w, lin_b, pooled);
  hipLaunchKernelGGL(lstm_fc_kernel, dim3(NB / 64), dim3(64), 0, stream,
                     pooled, w_ih, b_ih, w_hh, b_hh, fc_w, fc_b, out);
}